// Round 16
// baseline (239.662 us; speedup 1.0000x reference)
//
#include <hip/hip_runtime.h>
#include <hip/hip_bf16.h>
#include <hip/hip_fp16.h>

typedef _Float16 f16;
typedef _Float16 f16x8 __attribute__((ext_vector_type(8)));
typedef float f32x16 __attribute__((ext_vector_type(16)));
typedef unsigned int u32;

// Problem sizes (fixed)
#define BB 32
#define SS 2048
#define HH 1024
#define KK 1024

// ws layout (bytes)
#define WS_BP 0                            // packed Wv fp16: 2 MB
#define WS_HQ (2u*1024u*1024u)             // hq fp32: 32*1024*4 = 128 KB
#define WS_LP (WS_HQ + 131072u)            // logits partials: 4*32*2048*4 = 1 MB

__device__ __forceinline__ float tanh_f(float x) {
    // tanh(x) = 1 - 2/(e^{2x}+1); safe at +/-inf of exp
    float e = __expf(2.0f * x);
    return 1.0f - 2.0f * __builtin_amdgcn_rcpf(e + 1.0f);
}

// fp32x8 -> fp16x8 cvt + 16B LDS store
__device__ __forceinline__ void write_a16(char* dst, int off, float4 va, float4 vb) {
    union { f16 h[8]; uint4 u; } pk;
    pk.h[0] = (f16)va.x; pk.h[1] = (f16)va.y; pk.h[2] = (f16)va.z; pk.h[3] = (f16)va.w;
    pk.h[4] = (f16)vb.x; pk.h[5] = (f16)vb.y; pk.h[6] = (f16)vb.z; pk.h[7] = (f16)vb.w;
    *(uint4*)(dst + off) = pk.u;
}

// ---------------------------------------------------------------------------
// Pack Wv [k][n] fp32 -> fragment-ordered fp16 for mfma_f32_32x32x16_f16 B.
// Layout: BP[ntb(4)][kit(16)][wc(4)][ks(4)][ntl(2)][lane(64)][j(8)]
//   n = ntb*256 + wc*64 + ntl*32 + (lane&31); k = kit*64 + ks*16 + (lane>>5)*8 + j
// Per (block, wave, BK=64 epoch): ONE contiguous 8 KB chunk; ks01 half at +0,
// ks23 half at +4096.  (Byte-identical to round 15's verified pack.)
__global__ void pack_wv(const float* __restrict__ Wv, f16* __restrict__ BP) {
    int i = blockIdx.x * 256 + threadIdx.x;   // i = k*1024 + n
    int k = i >> 10, n = i & 1023;
    float v = Wv[i];
    int ntb = n >> 8, wc = (n >> 6) & 3, ntl = (n >> 5) & 1, nl = n & 31;
    int kit = k >> 6, ks = (k >> 4) & 3, lg = (k >> 3) & 1, j = k & 7;
    int lane = lg * 32 + nl;
    BP[((((((ntb * 16 + kit) * 4 + wc) * 4 + ks) * 2 + ntl) * 64 + lane) * 8) + j] = (f16)v;
}

// ---------------------------------------------------------------------------
// hq = query @ Wq + bq  (fp32). K split 4 ways, atomicAdd combine.
__global__ void hq_kernel(const float* __restrict__ query, const float* __restrict__ Wq,
                          const float* __restrict__ bq, float* __restrict__ hq) {
    int b = blockIdx.y;
    int h = (blockIdx.x & 3) * 256 + threadIdx.x;
    int v0 = (blockIdx.x >> 2) * 256;
    float acc = 0.f;
#pragma unroll 8
    for (int v = 0; v < 256; ++v)
        acc += query[b * 1024 + v0 + v] * Wq[(v0 + v) * 1024 + h];
    if (v0 == 0) acc += bq[h];
    atomicAdd(&hq[b * 1024 + h], acc);
}

// ---------------------------------------------------------------------------
// Fused 128x256x(K=1024) GEMM tile + tanh(hq+hv)·w row-reduction.
// Round-15 skeleton with wave tile 128x64 (acc[4][2] = 128 VGPR): B traffic
// halves chip-wide (2 GB -> 1 GB; total 3 -> 2 GB) and MFMA per wave-epoch
// doubles (32) -- bytes/MFMA 750 -> 500. B: half-split reg buffers
// bvA(ks01)/bvB(ks23) reloaded right after last use (>half-epoch L2 cover).
// A: HALF-SPLIT reg staging (4 float4 live at a time, each half covered by
// 16 MFMAs ~1024 cyc > HBM latency), frag-ordered LDS dbuf 2x16KB,
// conflict-free l*16 reads. One lgkm(0)+raw barrier per BK=64 epoch; vmcnt
// NEVER drained. 4 waves (256 thr) each spanning all 128 rows x 64 cols;
// launch_bounds(256,2) -> ~208 regs <= 256, 2 independent blocks/CU.
__launch_bounds__(256, 2)
__global__ void fused_main(const float* __restrict__ value, const f16* __restrict__ BP,
                           const float* __restrict__ hq, const float* __restrict__ wvec,
                           float* __restrict__ lpart) {
    __shared__ char A0[16384];                 // frag-ordered [mt(4)][ks(4)][lane][j]
    __shared__ char A1[16384];
    __shared__ float part[512];                // [wc(4)][row(128)]

    int bid = blockIdx.x;
    int tile = (bid & 7) * 256 + (bid >> 3);   // XCD swizzle (2048 % 8 == 0)
    int Mt = tile >> 2, ntb = tile & 3;        // 4 ntb of one Mt co-XCD
    int m0 = Mt << 7;                          // 128 rows
    int b = m0 >> 11, s0 = m0 & 2047;

    int tid = threadIdx.x;
    int wc = tid >> 6, l = tid & 63;
    int l31 = l & 31, lg = l >> 5;

    // ---- A staging: thread covers row tid>>1 (0..127), 32 floats at (tid&1)*32
    // (ks slices 2h2, 2h2+1 where h2 = tid&1), as two 16-float halves.
    int arow = tid >> 1, h2 = tid & 1;
    const float* aga = value + (size_t)(m0 + arow) * 1024 + h2 * 32;
    // write slot q2 (0..3): ks = 2*h2 + (q2>>1), lg8 = q2&1
    int aw[4];
#pragma unroll
    for (int q2 = 0; q2 < 4; ++q2)
        aw[q2] = ((arow >> 5) * 4 + h2 * 2 + (q2 >> 1)) * 1024
               + (((q2 & 1) * 32 + (arow & 31)) << 4);

    // ---- B per-wave base; epoch e chunk (8 KB) at + e*32768; halves +0/+4096
    const char* bg = (const char*)BP + (size_t)ntb * 524288 + (size_t)wc * 8192
                   + (size_t)l * 16;

    // ---- A frag read offsets (conflict-free lane*16): mt*4096 + ks*1024
    int a_rd = l * 16;

    const f32x16 fzero = {};
    f32x16 acc[4][2];
#pragma unroll
    for (int mt = 0; mt < 4; ++mt)
#pragma unroll
        for (int nt = 0; nt < 2; ++nt) acc[mt][nt] = fzero;

    f16x8 bvA[4], bvB[4];                      // B half-epoch buffers (ks01 / ks23)

#define COMPUTE_HALF(Ab, BV, kso) do { \
        _Pragma("unroll") \
        for (int ksl = 0; ksl < 2; ++ksl) { \
            f16x8 a0 = *(const f16x8*)((Ab) + 0 * 4096 + ((kso) + ksl) * 1024 + a_rd); \
            f16x8 a1 = *(const f16x8*)((Ab) + 1 * 4096 + ((kso) + ksl) * 1024 + a_rd); \
            f16x8 a2 = *(const f16x8*)((Ab) + 2 * 4096 + ((kso) + ksl) * 1024 + a_rd); \
            f16x8 a3 = *(const f16x8*)((Ab) + 3 * 4096 + ((kso) + ksl) * 1024 + a_rd); \
            __builtin_amdgcn_s_setprio(1); \
            acc[0][0] = __builtin_amdgcn_mfma_f32_32x32x16_f16(a0, (BV)[2 * ksl + 0], acc[0][0], 0, 0, 0); \
            acc[0][1] = __builtin_amdgcn_mfma_f32_32x32x16_f16(a0, (BV)[2 * ksl + 1], acc[0][1], 0, 0, 0); \
            acc[1][0] = __builtin_amdgcn_mfma_f32_32x32x16_f16(a1, (BV)[2 * ksl + 0], acc[1][0], 0, 0, 0); \
            acc[1][1] = __builtin_amdgcn_mfma_f32_32x32x16_f16(a1, (BV)[2 * ksl + 1], acc[1][1], 0, 0, 0); \
            acc[2][0] = __builtin_amdgcn_mfma_f32_32x32x16_f16(a2, (BV)[2 * ksl + 0], acc[2][0], 0, 0, 0); \
            acc[2][1] = __builtin_amdgcn_mfma_f32_32x32x16_f16(a2, (BV)[2 * ksl + 1], acc[2][1], 0, 0, 0); \
            acc[3][0] = __builtin_amdgcn_mfma_f32_32x32x16_f16(a3, (BV)[2 * ksl + 0], acc[3][0], 0, 0, 0); \
            acc[3][1] = __builtin_amdgcn_mfma_f32_32x32x16_f16(a3, (BV)[2 * ksl + 1], acc[3][1], 0, 0, 0); \
            __builtin_amdgcn_s_setprio(0); \
        } \
    } while (0)

#define LOADB(BV, e, half) do { \
        const char* bt_ = bg + (size_t)(e) * 32768 + (half) * 4096; \
        (BV)[0] = *(const f16x8*)(bt_); \
        (BV)[1] = *(const f16x8*)(bt_ + 1024); \
        (BV)[2] = *(const f16x8*)(bt_ + 2048); \
        (BV)[3] = *(const f16x8*)(bt_ + 3072); \
    } while (0)

    // ---- prologue: A(0)->A0 (both halves); B(0) both halves
    {
        const float4* ap = (const float4*)aga;
        float4 p0 = ap[0], p1 = ap[1], p2 = ap[2], p3 = ap[3];
        write_a16(A0, aw[0], p0, p1);
        write_a16(A0, aw[1], p2, p3);
        float4 p4 = ap[4], p5 = ap[5], p6 = ap[6], p7 = ap[7];
        write_a16(A0, aw[2], p4, p5);
        write_a16(A0, aw[3], p6, p7);
        LOADB(bvA, 0, 0);
        LOADB(bvB, 0, 1);
        asm volatile("s_waitcnt lgkmcnt(0)" ::: "memory");
        __builtin_amdgcn_s_barrier();
    }

    // ---- main loop: 16 epochs of BK=64; ONE lgkm(0)+barrier per epoch,
    // vmcnt never drained (A halves covered by 16 MFMAs each; B by >half-epoch).
#pragma unroll 1
    for (int e = 0; e < 16; ++e) {
        char* Ac = (e & 1) ? A1 : A0;
        char* An = (e & 1) ? A0 : A1;
        int en = (e < 15) ? e + 1 : 15;        // clamped dummies at tail (unused)
        const float4* ap = (const float4*)(aga + en * 64);

        // half 0: issue A(e+1) first 16 floats; compute ks01; reload bvA; stage
        float4 r0 = ap[0], r1 = ap[1], r2 = ap[2], r3 = ap[3];
        COMPUTE_HALF(Ac, bvA, 0);
        LOADB(bvA, en, 0);                     // used next epoch: half1+barrier cover
        write_a16(An, aw[0], r0, r1);
        write_a16(An, aw[1], r2, r3);

        // half 1: issue A(e+1) last 16 floats; compute ks23; reload bvB; stage
        float4 r4 = ap[4], r5 = ap[5], r6 = ap[6], r7 = ap[7];
        COMPUTE_HALF(Ac, bvB, 2);
        LOADB(bvB, en, 1);                     // used next epoch: barrier+half0 cover
        write_a16(An, aw[2], r4, r5);
        write_a16(An, aw[3], r6, r7);

        asm volatile("s_waitcnt lgkmcnt(0)" ::: "memory");
        __builtin_amdgcn_s_barrier();
    }
#undef COMPUTE_HALF
#undef LOADB

    // ---- epilogue: t = tanh(hq + hv) * w, pair-folded col reduction
    int h0 = ntb * 256 + wc * 64 + l31;   // ntl = 0
    int h1 = h0 + 32;                     // ntl = 1
    float hq0 = hq[b * 1024 + h0], hq1 = hq[b * 1024 + h1];
    float w0 = wvec[h0], w1 = wvec[h1];

#pragma unroll
    for (int mt = 0; mt < 4; ++mt) {
#pragma unroll
        for (int i = 0; i < 8; ++i) {
            float pa = tanh_f(hq0 + acc[mt][0][2 * i]) * w0
                     + tanh_f(hq1 + acc[mt][1][2 * i]) * w1;
            float pb = tanh_f(hq0 + acc[mt][0][2 * i + 1]) * w0
                     + tanh_f(hq1 + acc[mt][1][2 * i + 1]) * w1;
            float ea = __shfl_xor(pa, 1), eb = __shfl_xor(pb, 1);
            float g = (l & 1) ? (pb + eb) : (pa + ea);
            g += __shfl_xor(g, 2); g += __shfl_xor(g, 4);
            g += __shfl_xor(g, 8); g += __shfl_xor(g, 16);
            if (l31 < 2) {
                int r = 2 * i + (l31 & 1);
                int row = mt * 32 + (r & 3) + ((r >> 2) << 3) + (lg << 2);
                part[wc * 128 + row] = g;
            }
        }
    }
    __syncthreads();
    if (tid < 128) {
        float s = part[tid] + part[128 + tid] + part[256 + tid] + part[384 + tid];
        lpart[((size_t)ntb * 32 + b) * 2048 + s0 + tid] = s;
    }
}

// ---------------------------------------------------------------------------
// Masked softmax over S=2048 per b, summing the 4 N-block logit partials.
__global__ void softmax_kernel(const float* __restrict__ lp, const int* __restrict__ mask,
                               float* __restrict__ out) {
    __shared__ float redm[16];
    __shared__ float reds[16];
    const int P = 32 * 2048;
    int b = blockIdx.x, t = threadIdx.x;
    int wid = t >> 6, lane = t & 63;
    int i0 = b * 2048 + t, i1 = i0 + 1024;
    float l0 = lp[i0] + lp[P + i0] + lp[2 * P + i0] + lp[3 * P + i0];
    float l1 = lp[i1] + lp[P + i1] + lp[2 * P + i1] + lp[3 * P + i1];
    float a0 = mask[i0] ? l0 : -1e9f;
    float a1 = mask[i1] ? l1 : -1e9f;
    float mx = fmaxf(a0, a1);
#pragma unroll
    for (int off = 1; off < 64; off <<= 1) mx = fmaxf(mx, __shfl_xor(mx, off));
    if (lane == 0) redm[wid] = mx;
    __syncthreads();
    mx = redm[0];
#pragma unroll
    for (int i = 1; i < 16; ++i) mx = fmaxf(mx, redm[i]);
    float e0 = __expf(a0 - mx), e1 = __expf(a1 - mx);
    float s = e0 + e1;
#pragma unroll
    for (int off = 1; off < 64; off <<= 1) s += __shfl_xor(s, off);
    if (lane == 0) reds[wid] = s;
    __syncthreads();
    float tot = 0.f;
#pragma unroll
    for (int i = 0; i < 16; ++i) tot += reds[i];
    float inv = 1.0f / tot;
    out[b * 2048 + t] = e0 * inv;
    out[b * 2048 + 1024 + t] = e1 * inv;
}

// ---------------------------------------------------------------------------
extern "C" void kernel_launch(void* const* d_in, const int* in_sizes, int n_in,
                              void* d_out, int out_size, void* d_ws, size_t ws_size,
                              hipStream_t stream) {
    const float* query = (const float*)d_in[0];
    const float* value = (const float*)d_in[1];
    const int*   mask  = (const int*)d_in[2];
    const float* Wq    = (const float*)d_in[3];
    const float* bq    = (const float*)d_in[4];
    const float* Wv    = (const float*)d_in[5];
    const float* wv    = (const float*)d_in[6];

    char* ws = (char*)d_ws;
    f16*   BP    = (f16*)(ws + WS_BP);
    float* hq    = (float*)(ws + WS_HQ);
    float* lpart = (float*)(ws + WS_LP);
    float* out   = (float*)d_out;

    (void)hipMemsetAsync(hq, 0, BB * HH * sizeof(float), stream);
    pack_wv<<<(KK * HH) / 256, 256, 0, stream>>>(Wv, BP);
    hq_kernel<<<dim3(16, BB), 256, 0, stream>>>(query, Wq, bq, hq);
    fused_main<<<2048, 256, 0, stream>>>(value, BP, hq, wv, lpart);
    softmax_kernel<<<BB, 1024, 0, stream>>>(lpart, mask, out);
}